// Round 1
// baseline (680.086 us; speedup 1.0000x reference)
//
#include <hip/hip_runtime.h>
#include <hip/hip_bf16.h>
#include <stdint.h>

typedef short short8 __attribute__((ext_vector_type(8)));
typedef float f32x4 __attribute__((ext_vector_type(4)));

#define M_Q   25088   // B*H*W = 512*49
#define M_S   3136    // NS*HS*WS = 16*196
#define CK_   128
#define IN_   12544
#define SHIFTC 40.0f

__device__ __forceinline__ ushort f2bf(float f) {
  union { float f; uint32_t u; } v; v.f = f;
  uint32_t r = v.u + 0x7fffu + ((v.u >> 16) & 1u);
  return (ushort)(r >> 16);
}
__device__ __forceinline__ float bf2f(ushort u) {
  union { uint32_t u; float f; } v; v.u = ((uint32_t)u) << 16;
  return v.f;
}
__device__ __forceinline__ f32x4 mfma16(short8 a, short8 b, f32x4 c) {
  return __builtin_amdgcn_mfma_f32_16x16x32_bf16(a, b, c, 0, 0, 0);
}

// ---------------- pack/transpose kernels ----------------

// x [Bt,256,P] f32 -> Xp hi/lo [Bt*P][256] bf16 split
__global__ void pack_x(const float* __restrict__ src, ushort* __restrict__ hi,
                       ushort* __restrict__ lo, int P, int total) {
  int idx = blockIdx.x * 256 + threadIdx.x;
  if (idx >= total) return;
  int c = idx & 255;
  int row = idx >> 8;
  int b = row / P;
  int p = row - b * P;
  float v = src[(b * 256 + c) * P + p];
  ushort h = f2bf(v);
  hi[idx] = h;
  lo[idx] = f2bf(v - bf2f(h));
}

// stack conv weights [128,256]+[128,256] -> [256,256] hi/lo, plus biases
__global__ void pack_w(const float* __restrict__ Wqv, const float* __restrict__ Wqk,
                       const float* __restrict__ bqv, const float* __restrict__ bqk,
                       const float* __restrict__ Wsv, const float* __restrict__ Wsk,
                       const float* __restrict__ bsv, const float* __restrict__ bsk,
                       ushort* __restrict__ Wq_h, ushort* __restrict__ Wq_l, float* __restrict__ biasq,
                       ushort* __restrict__ Ws_h, ushort* __restrict__ Ws_l, float* __restrict__ biass) {
  int idx = blockIdx.x * 256 + threadIdx.x;
  if (idx < 65536) {
    int n = idx >> 8;
    const float* W = (n < 128) ? (Wqv + n * 256) : (Wqk + (n - 128) * 256);
    float v = W[idx & 255];
    ushort h = f2bf(v);
    Wq_h[idx] = h; Wq_l[idx] = f2bf(v - bf2f(h));
  } else if (idx < 131072) {
    int j = idx - 65536;
    int n = j >> 8;
    const float* W = (n < 128) ? (Wsv + n * 256) : (Wsk + (n - 128) * 256);
    float v = W[j & 255];
    ushort h = f2bf(v);
    Ws_h[j] = h; Ws_l[j] = f2bf(v - bf2f(h));
  } else if (idx < 131328) {
    int n = idx - 131072;
    biasq[n] = (n < 128) ? bqv[n] : bqk[n - 128];
  } else if (idx < 131584) {
    int n = idx - 131328;
    biass[n] = (n < 128) ? bsv[n] : bsk[n - 128];
  }
}

// QQ [25088][256] f32 -> fuse qv-part (bf16) + qk hi/lo [25088][128]
__global__ void pack_q(const float* __restrict__ QQ, ushort* __restrict__ fuse,
                       ushort* __restrict__ qk_h, ushort* __restrict__ qk_l) {
  int idx = blockIdx.x * 256 + threadIdx.x;  // exactly 25088*256
  int c = idx & 255;
  int q = idx >> 8;
  float v = QQ[idx];
  if (c < 128) {
    int b = q / 49, p = q - b * 49;
    fuse[b * IN_ + c * 49 + p] = f2bf(v);
  } else {
    int j = q * 128 + (c - 128);
    ushort h = f2bf(v);
    qk_h[j] = h; qk_l[j] = f2bf(v - bf2f(h));
  }
}

// SS [3136][256] f32 -> svT bf16 [128][3136] + skmat hi/lo [3136][128]
__global__ void pack_s(const float* __restrict__ SS, ushort* __restrict__ svT,
                       ushort* __restrict__ sk_h, ushort* __restrict__ sk_l) {
  int idx = blockIdx.x * 256 + threadIdx.x;  // exactly 3136*256
  int c = idx & 255;
  int k = idx >> 8;
  float v = SS[idx];
  if (c < 128) {
    svT[c * M_S + k] = f2bf(v);
  } else {
    int j = k * 128 + (c - 128);
    ushort h = f2bf(v);
    sk_h[j] = h; sk_l[j] = f2bf(v - bf2f(h));
  }
}

// ---------------- conv GEMM (split-bf16, 3-term) ----------------
// OUT[M][256] = A[M][256] x B[256][256]^T + bias ; block = 4 waves x 16 rows
__global__ __launch_bounds__(256) void gemm_conv(
    const ushort* __restrict__ Ah, const ushort* __restrict__ Al,
    const ushort* __restrict__ Bh, const ushort* __restrict__ Bl,
    const float* __restrict__ bias, float* __restrict__ out) {
  const int lane = threadIdx.x & 63, wv = threadIdx.x >> 6;
  const int r = lane & 15, g = lane >> 4;
  const int row0 = blockIdx.x * 64 + wv * 16;
  const ushort* arh = Ah + (row0 + r) * 256 + g * 8;
  const ushort* arl = Al + (row0 + r) * 256 + g * 8;
  f32x4 acc[16];
#pragma unroll
  for (int i = 0; i < 16; ++i) acc[i] = f32x4{0.f, 0.f, 0.f, 0.f};
#pragma unroll
  for (int kc = 0; kc < 8; ++kc) {
    short8 ah = *(const short8*)(arh + kc * 32);
    short8 al = *(const short8*)(arl + kc * 32);
    const ushort* bbh = Bh + r * 256 + kc * 32 + g * 8;
    const ushort* bbl = Bl + r * 256 + kc * 32 + g * 8;
#pragma unroll
    for (int nt = 0; nt < 16; ++nt) {
      short8 bh = *(const short8*)(bbh + nt * 16 * 256);
      short8 bl = *(const short8*)(bbl + nt * 16 * 256);
      acc[nt] = mfma16(ah, bh, acc[nt]);
      acc[nt] = mfma16(al, bh, acc[nt]);
      acc[nt] = mfma16(ah, bl, acc[nt]);
    }
  }
  const int qr = row0 + g * 4;
#pragma unroll
  for (int nt = 0; nt < 16; ++nt) {
    int n = nt * 16 + r;
    float bs = bias[n];
#pragma unroll
    for (int e = 0; e < 4; ++e) out[(qr + e) * 256 + n] = acc[nt][e] + bs;
  }
}

// ---------------- fused attention ----------------
// 1 wave per 32 query rows; loop 98 key tiles of 32.
__global__ __launch_bounds__(64) void attn_kernel(
    const ushort* __restrict__ Qh, const ushort* __restrict__ Ql,
    const ushort* __restrict__ Kh, const ushort* __restrict__ Kl,
    const ushort* __restrict__ Vt, ushort* __restrict__ fuse) {
  __shared__ ushort plds[2][16][32];
  const int lane = threadIdx.x;
  const int r = lane & 15, g = lane >> 4;
  const int q0 = blockIdx.x * 32;

  short8 aqh[2][4], aql[2][4];
#pragma unroll
  for (int mt = 0; mt < 2; ++mt)
#pragma unroll
    for (int kc = 0; kc < 4; ++kc) {
      const int rowq = q0 + mt * 16 + r;
      aqh[mt][kc] = *(const short8*)(Qh + rowq * 128 + kc * 32 + g * 8);
      aql[mt][kc] = *(const short8*)(Ql + rowq * 128 + kc * 32 + g * 8);
    }

  f32x4 acc[2][8];
#pragma unroll
  for (int mt = 0; mt < 2; ++mt)
#pragma unroll
    for (int ct = 0; ct < 8; ++ct) acc[mt][ct] = f32x4{0.f, 0.f, 0.f, 0.f};
  float den[2][4];
#pragma unroll
  for (int mt = 0; mt < 2; ++mt)
#pragma unroll
    for (int e = 0; e < 4; ++e) den[mt][e] = 0.f;

  for (int kb = 0; kb < M_S; kb += 32) {
    f32x4 lg[2][2];
#pragma unroll
    for (int kt = 0; kt < 2; ++kt) {
      const int krow = kb + kt * 16 + r;
      short8 bh[4], bl[4];
#pragma unroll
      for (int kc = 0; kc < 4; ++kc) {
        bh[kc] = *(const short8*)(Kh + krow * 128 + kc * 32 + g * 8);
        bl[kc] = *(const short8*)(Kl + krow * 128 + kc * 32 + g * 8);
      }
#pragma unroll
      for (int mt = 0; mt < 2; ++mt) {
        f32x4 c = f32x4{0.f, 0.f, 0.f, 0.f};
#pragma unroll
        for (int kc = 0; kc < 4; ++kc) {
          c = mfma16(aqh[mt][kc], bh[kc], c);
          c = mfma16(aql[mt][kc], bh[kc], c);
          c = mfma16(aqh[mt][kc], bl[kc], c);
        }
        lg[mt][kt] = c;
      }
    }
    // exp, den partials, stash P in LDS as [q][key] bf16
#pragma unroll
    for (int mt = 0; mt < 2; ++mt)
#pragma unroll
      for (int kt = 0; kt < 2; ++kt)
#pragma unroll
        for (int e = 0; e < 4; ++e) {
          float p = __expf(lg[mt][kt][e] - SHIFTC);
          den[mt][e] += p;
          plds[mt][g * 4 + e][kt * 16 + r] = f2bf(p);
        }
    __syncthreads();
    // PV: att += P(32k) x svT^T
#pragma unroll
    for (int mt = 0; mt < 2; ++mt) {
      short8 pf = *(const short8*)(&plds[mt][r][g * 8]);
#pragma unroll
      for (int ct = 0; ct < 8; ++ct) {
        short8 vf = *(const short8*)(Vt + (ct * 16 + r) * M_S + kb + g * 8);
        acc[mt][ct] = mfma16(pf, vf, acc[mt][ct]);
      }
    }
    __syncthreads();
  }

  // reduce den across the 16-lane group (keys are spread over lane bits 0-3)
#pragma unroll
  for (int mt = 0; mt < 2; ++mt)
#pragma unroll
    for (int e = 0; e < 4; ++e) {
      float d = den[mt][e];
      d += __shfl_xor(d, 1);
      d += __shfl_xor(d, 2);
      d += __shfl_xor(d, 4);
      d += __shfl_xor(d, 8);
      den[mt][e] = d;
    }
#pragma unroll
  for (int mt = 0; mt < 2; ++mt)
#pragma unroll
    for (int ct = 0; ct < 8; ++ct)
#pragma unroll
      for (int e = 0; e < 4; ++e) {
        int q = q0 + mt * 16 + g * 4 + e;
        int c = ct * 16 + r;
        int b = q / 49, p = q - b * 49;
        float val = acc[mt][ct][e] / den[mt][e];
        fuse[b * IN_ + 6272 + c * 49 + p] = f2bf(val);
      }
}

// ---------------- fc6: [512][12544] x [2048][12544]^T, split-K=4 ----------------
__global__ __launch_bounds__(256) void fc6_kernel(
    const ushort* __restrict__ fuse, const float* __restrict__ W6c,
    const float* __restrict__ W6r, float* __restrict__ part) {
  const int lane = threadIdx.x & 63, wv = threadIdx.x >> 6;
  const int r = lane & 15, g = lane >> 4;
  const int m0 = blockIdx.x * 256 + wv * 64;
  const int n0 = blockIdx.y * 64;
  const int kz = blockIdx.z;
  const int k0 = kz * 3136;
  f32x4 acc[4][4];
#pragma unroll
  for (int mt = 0; mt < 4; ++mt)
#pragma unroll
    for (int nt = 0; nt < 4; ++nt) acc[mt][nt] = f32x4{0.f, 0.f, 0.f, 0.f};
  const float* wrow[4];
#pragma unroll
  for (int nt = 0; nt < 4; ++nt) {
    int n = n0 + nt * 16 + r;
    wrow[nt] = (n < 1024) ? (W6c + (size_t)n * IN_) : (W6r + (size_t)(n - 1024) * IN_);
  }
  const ushort* arow[4];
#pragma unroll
  for (int mt = 0; mt < 4; ++mt) arow[mt] = fuse + (size_t)(m0 + mt * 16 + r) * IN_;

  for (int kk = 0; kk < 3136; kk += 32) {
    const int kcol = k0 + kk + g * 8;
    short8 af[4];
#pragma unroll
    for (int mt = 0; mt < 4; ++mt) af[mt] = *(const short8*)(arow[mt] + kcol);
    short8 bfr[4];
#pragma unroll
    for (int nt = 0; nt < 4; ++nt) {
      const float* wp = wrow[nt] + kcol;
      float4 w0 = *(const float4*)wp;
      float4 w1 = *(const float4*)(wp + 4);
      short8 bb;
      bb[0] = (short)f2bf(w0.x); bb[1] = (short)f2bf(w0.y);
      bb[2] = (short)f2bf(w0.z); bb[3] = (short)f2bf(w0.w);
      bb[4] = (short)f2bf(w1.x); bb[5] = (short)f2bf(w1.y);
      bb[6] = (short)f2bf(w1.z); bb[7] = (short)f2bf(w1.w);
      bfr[nt] = bb;
    }
#pragma unroll
    for (int mt = 0; mt < 4; ++mt)
#pragma unroll
      for (int nt = 0; nt < 4; ++nt) acc[mt][nt] = mfma16(af[mt], bfr[nt], acc[mt][nt]);
  }
#pragma unroll
  for (int mt = 0; mt < 4; ++mt)
#pragma unroll
    for (int nt = 0; nt < 4; ++nt)
#pragma unroll
      for (int e = 0; e < 4; ++e) {
        int m = m0 + mt * 16 + g * 4 + e;
        int n = n0 + nt * 16 + r;
        part[(size_t)kz * 1048576 + (size_t)m * 2048 + n] = acc[mt][nt][e];
      }
}

// sum split-K partials + bias + relu -> X7 bf16 [512][2048]
__global__ void fc6_reduce(const float* __restrict__ part, const float* __restrict__ b6c,
                           const float* __restrict__ b6r, ushort* __restrict__ X7) {
  int idx = blockIdx.x * 256 + threadIdx.x;  // exactly 512*2048
  int n = idx & 2047;
  float s = part[idx] + part[idx + 1048576] + part[idx + 2097152] + part[idx + 3145728];
  s += (n < 1024) ? b6c[n] : b6r[n - 1024];
  s = fmaxf(s, 0.f);
  X7[idx] = f2bf(s);
}

// ---------------- fc7: [512][1024] x [1024][1024]^T per half ----------------
__global__ __launch_bounds__(256) void fc7_kernel(
    const ushort* __restrict__ X7, const float* __restrict__ W7c,
    const float* __restrict__ W7r, const float* __restrict__ b7c,
    const float* __restrict__ b7r, float* __restrict__ out) {
  const int lane = threadIdx.x & 63, wv = threadIdx.x >> 6;
  const int r = lane & 15, g = lane >> 4;
  const int m0 = blockIdx.x * 64 + wv * 16;
  const int n0 = blockIdx.y * 64;
  const int half = (n0 >= 1024) ? 1 : 0;
  const int nn0 = n0 - half * 1024;
  const float* W7 = half ? W7r : W7c;
  const float* b7 = half ? b7r : b7c;
  f32x4 acc[4];
#pragma unroll
  for (int nt = 0; nt < 4; ++nt) acc[nt] = f32x4{0.f, 0.f, 0.f, 0.f};
  const ushort* arow = X7 + (size_t)(m0 + r) * 2048 + half * 1024;
  for (int kk = 0; kk < 1024; kk += 32) {
    short8 a = *(const short8*)(arow + kk + g * 8);
#pragma unroll
    for (int nt = 0; nt < 4; ++nt) {
      const float* wp = W7 + (size_t)(nn0 + nt * 16 + r) * 1024 + kk + g * 8;
      float4 w0 = *(const float4*)wp;
      float4 w1 = *(const float4*)(wp + 4);
      short8 bb;
      bb[0] = (short)f2bf(w0.x); bb[1] = (short)f2bf(w0.y);
      bb[2] = (short)f2bf(w0.z); bb[3] = (short)f2bf(w0.w);
      bb[4] = (short)f2bf(w1.x); bb[5] = (short)f2bf(w1.y);
      bb[6] = (short)f2bf(w1.z); bb[7] = (short)f2bf(w1.w);
      acc[nt] = mfma16(a, bb, acc[nt]);
    }
  }
  float* obase = out + (size_t)half * 524288;
#pragma unroll
  for (int nt = 0; nt < 4; ++nt) {
#pragma unroll
    for (int e = 0; e < 4; ++e) {
      int m = m0 + g * 4 + e;
      int n = nn0 + nt * 16 + r;
      obase[(size_t)m * 1024 + n] = fmaxf(acc[nt][e] + b7[n], 0.f);
    }
  }
}

// ---------------- launch ----------------
extern "C" void kernel_launch(void* const* d_in, const int* in_sizes, int n_in,
                              void* d_out, int out_size, void* d_ws, size_t ws_size,
                              hipStream_t stream) {
  const float* x    = (const float*)d_in[0];
  const float* sup  = (const float*)d_in[1];
  const float* Wqv  = (const float*)d_in[2];
  const float* bqv  = (const float*)d_in[3];
  const float* Wqk  = (const float*)d_in[4];
  const float* bqk  = (const float*)d_in[5];
  const float* Wsv  = (const float*)d_in[6];
  const float* bsv  = (const float*)d_in[7];
  const float* Wsk  = (const float*)d_in[8];
  const float* bsk  = (const float*)d_in[9];
  const float* W6c  = (const float*)d_in[10];
  const float* b6c  = (const float*)d_in[11];
  const float* W7c  = (const float*)d_in[12];
  const float* b7c  = (const float*)d_in[13];
  const float* W6r  = (const float*)d_in[14];
  const float* b6r  = (const float*)d_in[15];
  const float* W7r  = (const float*)d_in[16];
  const float* b7r  = (const float*)d_in[17];
  float* out = (float*)d_out;

  char* base = (char*)d_ws;
  size_t off = 0;
  auto alloc = [&](size_t bytes) {
    char* p = base + off;
    off += (bytes + 255) & ~(size_t)255;
    return p;
  };
  ushort* Xp_h = (ushort*)alloc((size_t)M_Q * 256 * 2);
  ushort* Xp_l = (ushort*)alloc((size_t)M_Q * 256 * 2);
  ushort* Xs_h = (ushort*)alloc((size_t)M_S * 256 * 2);
  ushort* Xs_l = (ushort*)alloc((size_t)M_S * 256 * 2);
  ushort* Wq_h = (ushort*)alloc(65536 * 2);
  ushort* Wq_l = (ushort*)alloc(65536 * 2);
  ushort* Ws_h = (ushort*)alloc(65536 * 2);
  ushort* Ws_l = (ushort*)alloc(65536 * 2);
  float*  biasq = (float*)alloc(256 * 4);
  float*  biass = (float*)alloc(256 * 4);
  float*  QQ   = (float*)alloc((size_t)M_Q * 256 * 4);
  float*  SS   = (float*)alloc((size_t)M_S * 256 * 4);
  ushort* fuse = (ushort*)alloc((size_t)512 * IN_ * 2);
  ushort* qk_h = (ushort*)alloc((size_t)M_Q * 128 * 2);
  ushort* qk_l = (ushort*)alloc((size_t)M_Q * 128 * 2);
  ushort* sk_h = (ushort*)alloc((size_t)M_S * 128 * 2);
  ushort* sk_l = (ushort*)alloc((size_t)M_S * 128 * 2);
  ushort* svT  = (ushort*)alloc((size_t)M_S * 128 * 2);
  float*  part = (float*)alloc((size_t)4 * 512 * 2048 * 4);
  ushort* X7   = (ushort*)alloc((size_t)512 * 2048 * 2);
  if (off > ws_size) return;  // insufficient scratch; validation will show poison

  // 1) pack inputs to bf16 hi/lo, token-major
  pack_x<<<dim3(25088), dim3(256), 0, stream>>>(x, Xp_h, Xp_l, 49, M_Q * 256);
  pack_x<<<dim3(3136), dim3(256), 0, stream>>>(sup, Xs_h, Xs_l, 196, M_S * 256);
  pack_w<<<dim3(515), dim3(256), 0, stream>>>(Wqv, Wqk, bqv, bqk, Wsv, Wsk, bsv, bsk,
                                              Wq_h, Wq_l, biasq, Ws_h, Ws_l, biass);
  // 2) 1x1 convs (split-bf16 GEMM, fp32-accurate)
  gemm_conv<<<dim3(392), dim3(256), 0, stream>>>(Xp_h, Xp_l, Wq_h, Wq_l, biasq, QQ);
  gemm_conv<<<dim3(49), dim3(256), 0, stream>>>(Xs_h, Xs_l, Ws_h, Ws_l, biass, SS);
  // 3) rearrange conv outputs
  pack_q<<<dim3(25088), dim3(256), 0, stream>>>(QQ, fuse, qk_h, qk_l);
  pack_s<<<dim3(3136), dim3(256), 0, stream>>>(SS, svT, sk_h, sk_l);
  // 4) fused attention -> att half of fuse
  attn_kernel<<<dim3(784), dim3(64), 0, stream>>>(qk_h, qk_l, sk_h, sk_l, svT, fuse);
  // 5) fc6 (split-K deterministic) + reduce+relu
  fc6_kernel<<<dim3(2, 32, 4), dim3(256), 0, stream>>>(fuse, W6c, W6r, part);
  fc6_reduce<<<dim3(4096), dim3(256), 0, stream>>>(part, b6c, b6r, X7);
  // 6) fc7 + bias + relu -> d_out (xc then xr)
  fc7_kernel<<<dim3(8, 32), dim3(256), 0, stream>>>(X7, W7c, W7r, b7c, b7r, out);
}